// Round 1
// 480.373 us; speedup vs baseline: 1.0200x; 1.0200x over previous
//
#include <hip/hip_runtime.h>
#include <cmath>

// Problem constants (from reference setup_inputs)
constexpr int Bdim = 64;
constexpr int Fdim = 4096;
constexpr int Edim = 256;
constexpr int Hdim = 512;
constexpr int Udim = 512;

typedef __attribute__((ext_vector_type(8))) short short8;   // 8 bf16 (16B)
typedef __attribute__((ext_vector_type(4))) float f32x4;

// ---------------------------------------------------------------------------
// Helpers
// ---------------------------------------------------------------------------
__device__ __forceinline__ unsigned short f2bf(float f) {
    unsigned int u = __float_as_uint(f);
    u += 0x7FFFu + ((u >> 16) & 1u);   // RNE; inputs finite
    return (unsigned short)(u >> 16);
}
__device__ __forceinline__ unsigned int pack2(float lo, float hi) {
    return (unsigned int)f2bf(lo) | ((unsigned int)f2bf(hi) << 16);
}
__device__ __forceinline__ float tanh_fast(float x) {
    float e = __expf(2.0f * x);
    return 1.0f - 2.0f * __builtin_amdgcn_rcpf(e + 1.0f);
}
// async global->LDS, 16B per lane; lds dest is wave-uniform base + lane*16
__device__ __forceinline__ void gload_lds16(const void* g, void* l) {
    __builtin_amdgcn_global_load_lds(
        (const __attribute__((address_space(1))) unsigned int*)g,
        (__attribute__((address_space(3))) unsigned int*)l, 16, 0, 0);
}

// ---------------------------------------------------------------------------
// Kernel 1 (fused prep): blocks 0..127   : cb[b][u] = W1b[u]+W2b[u]+hidden.W2
//                        blocks 128..159 : W1 -> transposed/swizzled bf16 W1Ts
//                        blocks 160..175 : zero ctx (replaces hipMemsetAsync)
// ---------------------------------------------------------------------------
__global__ __launch_bounds__(256) void prep_kernel(
    const float* __restrict__ hidden, const float* __restrict__ W2,
    const float* __restrict__ W1b, const float* __restrict__ W2b,
    float* __restrict__ cb,
    const float* __restrict__ W1, unsigned short* __restrict__ Th,
    float* __restrict__ ctx, const int do_t)
{
    const int bid = blockIdx.x;
    const int tid = threadIdx.x;

    if (bid < 128) {
        // ---- proj_h: grid was (64 b, 2 u-chunks) ----
        const int b = bid >> 1;
        const int u = (bid & 1) * 256 + tid;
        const float* hb = hidden + (size_t)b * Hdim;
        float acc = 0.f;
        #pragma unroll 8
        for (int h = 0; h < Hdim; ++h)
            acc = fmaf(hb[h], W2[(size_t)h * Udim + u], acc);
        cb[(size_t)b * Udim + u] = acc + W1b[u] + W2b[u];
    } else if (bid < 160) {
        // ---- w1t: W1 (E,U) fp32 -> bf16 [U][E] with 16B-chunk XOR swizzle
        // (chunk c of row u stored at c ^ (u&7); global_load_lds forbids pad)
        if (!do_t) return;
        __shared__ unsigned short sT[64][72];
        const int k  = bid - 128;            // 0..31 : (4 e-tiles) x (8 u-tiles)
        const int e0 = (k & 3) * 64, u0 = (k >> 2) * 64;
        const int ue = tid & 63, er = tid >> 6;
        #pragma unroll
        for (int it = 0; it < 16; ++it) {
            const int e = er + it * 4;
            sT[ue][e] = f2bf(W1[(size_t)(e0 + e) * Udim + u0 + ue]);
        }
        __syncthreads();
        const int ur = tid >> 2, cq = tid & 3;
        const int u = u0 + ur, s = u & 7;
        const int cA = (e0 >> 3) + cq * 2;   // global 16B-chunk index
        uint4 a  = *(const uint4*)&sT[ur][cq * 16];
        uint4 b2 = *(const uint4*)&sT[ur][cq * 16 + 8];
        unsigned short* dst = Th + (size_t)u * Edim;
        *(uint4*)(dst + ((cA ^ s) << 3))       = a;
        *(uint4*)(dst + (((cA + 1) ^ s) << 3)) = b2;
    } else {
        // ---- zero ctx: 16 blocks x 256 threads x float4 = 16384 floats ----
        const int idx = (bid - 160) * 256 + tid;
        ((float4*)ctx)[idx] = make_float4(0.f, 0.f, 0.f, 0.f);
    }
}

// ---------------------------------------------------------------------------
// Kernel 2 (dominant): scores via bf16 MFMA, spill-free A-in-registers.
// Block: 128 f-rows x full U; 4 waves x 32 f-rows. A = af[2][8] (64 VGPRs).
// B: 16 u-passes of 32 rows (16 KB) double-buffered in the SAME 33,792 B LDS
// (occupancy preserved) with the next window's global_load_lds issued BEFORE
// the current window's MFMA+tanh — drain hidden under ~800+ cy of compute.
// One barrier per pass (was two). Fused tanh+V-dot epilogue.
// ---------------------------------------------------------------------------
__global__ __launch_bounds__(256, 2) void score_mfma4_kernel(
    const float* __restrict__ feat,            // [B][F][E] fp32
    const unsigned short* __restrict__ W1Ts,   // [U][E] bf16, chunk-swizzled
    const float* __restrict__ Vw, const float* __restrict__ Vb,
    const float* __restrict__ cb, float* __restrict__ scores)
{
    __shared__ unsigned short lds[16896];   // 33,792 B: A-scratch / B dbuf

    const int b    = blockIdx.y;
    const int f0   = blockIdx.x * 128;
    const int tid  = threadIdx.x;
    const int lane = tid & 63;
    const int w    = tid >> 6;          // wave id; 32 f-rows each
    const int ln15 = lane & 15;
    const int kq   = lane >> 4;         // 0..3
    const int swz  = ln15 & 7;

    // ---- Phase A: stage+convert 32 f-rows into af[2][8] (64 VGPRs) ----
    short8 af[2][8];
    {
        unsigned short* sAw = lds + w * 4224;   // 16 rows x 264 per wave
        const float* gA = feat + ((size_t)(b * Fdim + f0 + w * 32)) * Edim;
        #pragma unroll
        for (int h = 0; h < 2; ++h) {
            #pragma unroll
            for (int r = 0; r < 16; ++r) {
                float4 v = *(const float4*)(gA + (size_t)(h * 16 + r) * Edim + lane * 4);
                uint2 p; p.x = pack2(v.x, v.y); p.y = pack2(v.z, v.w);
                *(uint2*)&sAw[r * 264 + lane * 4] = p;
            }
            #pragma unroll
            for (int k8 = 0; k8 < 8; ++k8)
                af[h][k8] = *(const short8*)&sAw[ln15 * 264 + k8 * 32 + kq * 8];
        }
    }
    __syncthreads();   // all waves done with A scratch before B overwrites it

    float sacc[2][4] = {};   // [mi][r]
    const float* cbB = cb + (size_t)b * Udim;

    // ---- prologue: stage pass 0 (u-rows 0..31, 16 KB) into buf0 ----
    {
        const char* gB = (const char*)W1Ts;
        #pragma unroll
        for (int t = 0; t < 4; ++t) {
            const int chunk = w * 4 + t;   // 16 x 1 KB
            gload_lds16(gB + (size_t)chunk * 1024 + lane * 16,
                        (char*)lds + chunk * 1024);
        }
    }
    __syncthreads();

    for (int p = 0; p < 16; ++p) {
        // issue-early prefetch of next window into the other buffer
        if (p < 15) {
            const char* gB = (const char*)(W1Ts + (size_t)(p + 1) * 32 * Edim);
            char* lb = (char*)lds + ((p + 1) & 1) * 16384;
            #pragma unroll
            for (int t = 0; t < 4; ++t) {
                const int chunk = w * 4 + t;
                gload_lds16(gB + (size_t)chunk * 1024 + lane * 16,
                            lb + chunk * 1024);
            }
        }

        const unsigned short* bw = lds + (p & 1) * 8192;   // current window
        const int ub = p * 32;
        const float cu0 = cbB[ub + ln15],     cu1 = cbB[ub + 16 + ln15];
        const float vv0 = Vw[ub + ln15],      vv1 = Vw[ub + 16 + ln15];
        f32x4 acc[2][2] = {};
        #pragma unroll
        for (int k8 = 0; k8 < 8; ++k8) {
            const int co = ((k8 * 4 + kq) ^ swz) * 8;   // swizzled chunk
            short8 b0 = *(const short8*)&bw[ln15 * 256 + co];
            short8 b1 = *(const short8*)&bw[(16 + ln15) * 256 + co];
            #pragma unroll
            for (int mi = 0; mi < 2; ++mi) {
                acc[mi][0] = __builtin_amdgcn_mfma_f32_16x16x32_bf16(
                    af[mi][k8], b0, acc[mi][0], 0, 0, 0);
                acc[mi][1] = __builtin_amdgcn_mfma_f32_16x16x32_bf16(
                    af[mi][k8], b1, acc[mi][1], 0, 0, 0);
            }
        }
        // fused epilogue: tanh + V-dot into running per-f partials
        #pragma unroll
        for (int mi = 0; mi < 2; ++mi)
            #pragma unroll
            for (int r = 0; r < 4; ++r)
                sacc[mi][r] += tanh_fast(acc[mi][0][r] + cu0) * vv0
                             + tanh_fast(acc[mi][1][r] + cu1) * vv1;

        if (p < 15) __syncthreads();   // reads done before buf reuse; drains
    }                                  // prefetch (covered by compute above)

    // ---- reduce over u-lanes (ln15), store raw scores (+Vb) ----
    const float vb = Vb[0];
    #pragma unroll
    for (int mi = 0; mi < 2; ++mi)
        #pragma unroll
        for (int r = 0; r < 4; ++r) {
            float s = sacc[mi][r];
            s += __shfl_xor(s, 1);
            s += __shfl_xor(s, 2);
            s += __shfl_xor(s, 4);
            s += __shfl_xor(s, 8);
            if (ln15 == 0)
                scores[(size_t)b * Fdim + f0 + w * 32 + mi * 16 + kq * 4 + r] = s + vb;
        }
}

// ---------------------------------------------------------------------------
// Fallback fp32 score kernel — used only if ws too small
// ---------------------------------------------------------------------------
constexpr int TFt = 64;
constexpr int TUt = 64;
constexpr int LDR = Edim + 4;

__global__ __launch_bounds__(256) void score_kernel(
    const float* __restrict__ feat, const float* __restrict__ W1,
    const float* __restrict__ Vw, const float* __restrict__ Vb,
    const float* __restrict__ cb, float* __restrict__ scores)
{
    __shared__ float sA[TFt * LDR];
    __shared__ float sW[TUt * LDR];

    const int b   = blockIdx.y;
    const int f0  = blockIdx.x * TFt;
    const int tid = threadIdx.x;
    const int tf  = tid >> 4;
    const int tu  = tid & 15;

    {
        const float4* gA = (const float4*)(feat + ((size_t)b * Fdim + f0) * Edim);
        #pragma unroll
        for (int it = 0; it < 16; ++it) {
            const int i = tid + it * 256;
            const int f = i >> 6;
            const int qq = i & 63;
            const float4 v = gA[i];
            *(float4*)&sA[f * LDR + 4 * qq] = v;
        }
    }

    float sacc[4] = {0.f, 0.f, 0.f, 0.f};
    const float* cbb = cb + (size_t)b * Udim;

    for (int uc = 0; uc < Udim; uc += TUt) {
        __syncthreads();
        #pragma unroll
        for (int it = 0; it < 16; ++it) {
            const int i = tid + it * 256;
            const int e = i >> 4;
            const int qq = i & 15;
            const float4 v = *(const float4*)(W1 + (size_t)e * Udim + uc + 4 * qq);
            sW[(4 * qq + 0) * LDR + e] = v.x;
            sW[(4 * qq + 1) * LDR + e] = v.y;
            sW[(4 * qq + 2) * LDR + e] = v.z;
            sW[(4 * qq + 3) * LDR + e] = v.w;
        }
        __syncthreads();

        float acc[4][4] = {};
        #pragma unroll 4
        for (int e = 0; e < Edim; e += 4) {
            float4 a0 = *(const float4*)&sA[(tf +  0) * LDR + e];
            float4 a1 = *(const float4*)&sA[(tf + 16) * LDR + e];
            float4 a2 = *(const float4*)&sA[(tf + 32) * LDR + e];
            float4 a3 = *(const float4*)&sA[(tf + 48) * LDR + e];
            float4 w0 = *(const float4*)&sW[(tu +  0) * LDR + e];
            float4 w1 = *(const float4*)&sW[(tu + 16) * LDR + e];
            float4 w2 = *(const float4*)&sW[(tu + 32) * LDR + e];
            float4 w3 = *(const float4*)&sW[(tu + 48) * LDR + e];
            #define FMA4(i, j, A, W)                         \
                acc[i][j] = fmaf(A.x, W.x, acc[i][j]);       \
                acc[i][j] = fmaf(A.y, W.y, acc[i][j]);       \
                acc[i][j] = fmaf(A.z, W.z, acc[i][j]);       \
                acc[i][j] = fmaf(A.w, W.w, acc[i][j]);
            FMA4(0,0,a0,w0) FMA4(0,1,a0,w1) FMA4(0,2,a0,w2) FMA4(0,3,a0,w3)
            FMA4(1,0,a1,w0) FMA4(1,1,a1,w1) FMA4(1,2,a1,w2) FMA4(1,3,a1,w3)
            FMA4(2,0,a2,w0) FMA4(2,1,a2,w1) FMA4(2,2,a2,w2) FMA4(2,3,a2,w3)
            FMA4(3,0,a3,w0) FMA4(3,1,a3,w1) FMA4(3,2,a3,w2) FMA4(3,3,a3,w3)
            #undef FMA4
        }

        #pragma unroll
        for (int j = 0; j < 4; ++j) {
            const int u = uc + tu + 16 * j;
            const float vw = Vw[u];
            const float cuv = cbb[u];
            #pragma unroll
            for (int i = 0; i < 4; ++i)
                sacc[i] = fmaf(tanhf(acc[i][j] + cuv), vw, sacc[i]);
        }
    }

    const float vb = Vb[0];
    #pragma unroll
    for (int i = 0; i < 4; ++i) {
        float s = sacc[i];
        s += __shfl_xor(s, 1);
        s += __shfl_xor(s, 2);
        s += __shfl_xor(s, 4);
        s += __shfl_xor(s, 8);
        if (tu == 0)
            scores[(size_t)b * Fdim + f0 + tf + 16 * i] = s + vb;
    }
}

// ---------------------------------------------------------------------------
// Kernel 3: per-b softmax statistics (max, 1/sum) — shfl reduce, 2 barriers
// ---------------------------------------------------------------------------
__global__ __launch_bounds__(256) void softmax_stats_kernel(
    const float* __restrict__ sc, float2* __restrict__ st)
{
    __shared__ float red[8];
    const int b   = blockIdx.x;
    const int tid = threadIdx.x;
    const float* row = sc + (size_t)b * Fdim;

    float v[16];
    float m = -INFINITY;
    #pragma unroll
    for (int i = 0; i < 16; ++i) {
        v[i] = row[tid + 256 * i];
        m = fmaxf(m, v[i]);
    }
    #pragma unroll
    for (int off = 1; off < 64; off <<= 1)
        m = fmaxf(m, __shfl_xor(m, off));
    if ((tid & 63) == 0) red[tid >> 6] = m;
    __syncthreads();
    m = fmaxf(fmaxf(red[0], red[1]), fmaxf(red[2], red[3]));

    float s = 0.f;
    #pragma unroll
    for (int i = 0; i < 16; ++i)
        s += expf(v[i] - m);
    #pragma unroll
    for (int off = 1; off < 64; off <<= 1)
        s += __shfl_xor(s, off);
    if ((tid & 63) == 0) red[4 + (tid >> 6)] = s;
    __syncthreads();
    if (tid == 0) {
        const float tot = red[4] + red[5] + red[6] + red[7];
        st[b] = make_float2(m, 1.0f / tot);
    }
}

// ---------------------------------------------------------------------------
// Kernel 4 (fused): weights = exp(s-m)*inv (written once) + context accum.
// float4 loads (16 B/lane, full 1 KB row per wave per instr), LDS-broadcast
// weights, 4-way LDS reduce, then one atomicAdd set per block.
// ---------------------------------------------------------------------------
__global__ __launch_bounds__(256) void ctxnorm_kernel(
    const float* __restrict__ feat, const float2* __restrict__ st,
    float* __restrict__ wts, float* __restrict__ ctx)
{
    __shared__ float  wl[256];
    __shared__ float4 sred[256];

    const int b   = blockIdx.y;
    const int f0  = blockIdx.x * 256;
    const int tid = threadIdx.x;

    const float2 s2 = st[b];
    const size_t wix = (size_t)b * Fdim + f0 + tid;
    const float wgt = expf(wts[wix] - s2.x) * s2.y;
    wts[wix] = wgt;            // normalized attention weights (output #2)
    wl[tid]  = wgt;
    __syncthreads();

    const int e4 = tid & 63;   // float4 column
    const int fg = tid >> 6;   // f-row group (0..3)
    const float4* fp = (const float4*)(feat + ((size_t)b * Fdim + f0) * Edim);

    float4 a = make_float4(0.f, 0.f, 0.f, 0.f);
    #pragma unroll 8
    for (int i = 0; i < 64; ++i) {
        const int f = i * 4 + fg;
        const float4 v = fp[(size_t)f * 64 + e4];
        const float wv = wl[f];
        a.x = fmaf(wv, v.x, a.x);
        a.y = fmaf(wv, v.y, a.y);
        a.z = fmaf(wv, v.z, a.z);
        a.w = fmaf(wv, v.w, a.w);
    }
    sred[tid] = a;
    __syncthreads();

    if (fg == 0) {
        const float4 r0 = sred[e4];
        const float4 r1 = sred[64 + e4];
        const float4 r2 = sred[128 + e4];
        const float4 r3 = sred[192 + e4];
        float* cp = ctx + (size_t)b * Edim + e4 * 4;
        atomicAdd(cp + 0, r0.x + r1.x + r2.x + r3.x);
        atomicAdd(cp + 1, r0.y + r1.y + r2.y + r3.y);
        atomicAdd(cp + 2, r0.z + r1.z + r2.z + r3.z);
        atomicAdd(cp + 3, r0.w + r1.w + r2.w + r3.w);
    }
}

// ---------------------------------------------------------------------------
extern "C" void kernel_launch(void* const* d_in, const int* in_sizes, int n_in,
                              void* d_out, int out_size, void* d_ws, size_t ws_size,
                              hipStream_t stream)
{
    const float* features = (const float*)d_in[0];
    const float* hidden   = (const float*)d_in[1];
    const float* W1w      = (const float*)d_in[2];
    const float* W1b      = (const float*)d_in[3];
    const float* W2w      = (const float*)d_in[4];
    const float* W2b      = (const float*)d_in[5];
    const float* Vw       = (const float*)d_in[6];
    const float* Vb       = (const float*)d_in[7];

    float* ctx = (float*)d_out;                       // (B,E)
    float* wts = (float*)d_out + (size_t)Bdim * Edim; // (B,F)

    // Workspace: cb (128 KiB) | stats (512 B) | W1Ts (256 KiB bf16 swizzled)
    float*  cb    = (float*)d_ws;
    float2* stats = (float2*)((char*)d_ws + 131072);
    unsigned short* W1Ts = (unsigned short*)((char*)d_ws + 131584);
    const size_t NEED = 131584 + (size_t)Udim * Edim * 2;
    const int mfma_ok = (ws_size >= NEED) ? 1 : 0;

    // prep: proj_h (128) + W1 transpose (32) + ctx zero (16) in one dispatch
    prep_kernel<<<176, 256, 0, stream>>>(hidden, W2w, W1b, W2b, cb,
                                         W1w, W1Ts, ctx, mfma_ok);

    if (mfma_ok) {
        dim3 sgrid(Fdim / 128, Bdim);       // (32, 64)
        score_mfma4_kernel<<<sgrid, 256, 0, stream>>>(features, W1Ts, Vw, Vb, cb, wts);
    } else {
        dim3 sgrid(Fdim / TFt, Bdim);
        score_kernel<<<sgrid, 256, 0, stream>>>(features, W1w, Vw, Vb, cb, wts);
    }

    softmax_stats_kernel<<<Bdim, 256, 0, stream>>>(wts, stats);

    dim3 cgrid(Fdim / 256, Bdim);           // (16, 64)
    ctxnorm_kernel<<<cgrid, 256, 0, stream>>>(features, stats, wts, ctx);
}